// Round 4
// baseline (1883.412 us; speedup 1.0000x reference)
//
#include <hip/hip_runtime.h>
#include <hip/hip_bf16.h>

#define NEG_SLOPE 0.01f
// bucket sort: rows per bucket = 256 (bucket id = row >> 8)
// Packing assumes col < 2^24 and rows-per-bucket = 256 (rowlow in top 8 bits).

__device__ __forceinline__ void atomAddF(float* p, float v) {
    unsafeAtomicAdd(p, v);   // HW global_atomic_add_f32 (avoids CAS fallback)
}

// ---- phase 1: bucket histogram (LDS-aggregated) -------------------------
__global__ void bucket_hist_kernel(const int* __restrict__ row, int* __restrict__ bhist,
                                   int E, int NB) {
    __shared__ int lh[512];
    for (int t = threadIdx.x; t < 512; t += blockDim.x) lh[t] = 0;
    __syncthreads();
    int i = blockIdx.x * blockDim.x + threadIdx.x;
    if (i < E) atomicAdd(&lh[row[i] >> 8], 1);
    __syncthreads();
    for (int t = threadIdx.x; t < NB; t += blockDim.x)
        if (lh[t]) atomicAdd(&bhist[t], lh[t]);
}

// ---- phase 2: exclusive scan of bucket counts (NB <= 512), init cursors -
__global__ void bucket_scan_kernel(const int* __restrict__ bhist, int* __restrict__ bbase,
                                   int* __restrict__ bcursor, int* __restrict__ rowptr,
                                   int NB, int N, int E) {
    __shared__ int s[512];
    int t = threadIdx.x;
    int v = (t < NB) ? bhist[t] : 0;
    s[t] = v;
    __syncthreads();
    for (int off = 1; off < 512; off <<= 1) {
        int x = (t >= off) ? s[t - off] : 0;
        __syncthreads();
        s[t] += x;
        __syncthreads();
    }
    if (t < NB) { bbase[t] = s[t] - v; bcursor[t] = s[t] - v; }
    if (t == 0) { bbase[NB] = E; rowptr[N] = E; }
}

// ---- phase 3: scatter edges into bucket-contiguous staging --------------
// staging word0 = col | (row&255)<<24 ; word1 = attr bits
__global__ void bucket_scatter_kernel(const int* __restrict__ row, const int* __restrict__ col,
                                      const float* __restrict__ attr, int* __restrict__ bcursor,
                                      int2* __restrict__ staging, int E) {
    int e = blockIdx.x * blockDim.x + threadIdx.x;
    if (e >= E) return;
    int r = row[e], c = col[e];
    float a = attr[e];
    int pos = atomicAdd(&bcursor[r >> 8], 1);
    staging[pos] = make_int2(c | ((r & 255) << 24), __float_as_int(a));
}

// ---- phase 4: per-bucket finalize: rowptr, dinv, sorted CSR -------------
// One block per bucket. Block owns its 256 rows exclusively -> no global atomics.
__global__ void bucket_finalize_kernel(const int* __restrict__ bbase,
                                       const int2* __restrict__ staging,
                                       int2* __restrict__ sorted, int* __restrict__ rowptr,
                                       float* __restrict__ dinv, int N) {
    __shared__ int lcount[256];
    __shared__ int lscan[256];
    __shared__ float ldeg[256];
    int t = threadIdx.x;
    int b = blockIdx.x;
    int base = bbase[b], end = bbase[b + 1];
    lcount[t] = 0;
    ldeg[t] = 0.f;
    __syncthreads();
    for (int e = base + t; e < end; e += 256) {
        int2 w = staging[e];
        int rl = (w.x >> 24) & 255;
        atomicAdd(&lcount[rl], 1);
        atomicAdd(&ldeg[rl], __int_as_float(w.y));
    }
    __syncthreads();
    lscan[t] = lcount[t];
    __syncthreads();
    for (int off = 1; off < 256; off <<= 1) {
        int x = (t >= off) ? lscan[t - off] : 0;
        __syncthreads();
        lscan[t] += x;
        __syncthreads();
    }
    int excl = lscan[t] - lcount[t];
    int grow = (b << 8) + t;
    if (grow < N) {
        rowptr[grow] = base + excl;
        float d = ldeg[t];
        dinv[grow] = d > 0.f ? rsqrtf(d) : 0.f;
    }
    __syncthreads();
    lcount[t] = excl;           // reuse as local cursor
    __syncthreads();
    for (int e = base + t; e < end; e += 256) {
        int2 w = staging[e];
        int rl = (w.x >> 24) & 255;
        int pos = base + atomicAdd(&lcount[rl], 1);
        sorted[pos] = make_int2(w.x & 0xFFFFFF, w.y);   // {col, attr}
    }
}

// ---- h1 = leaky_relu(x @ w1 + b1), x:(N,20) w:(20,32) -------------------
__global__ void h1_kernel(const float* __restrict__ x, const float* __restrict__ w,
                          const float* __restrict__ b, float* __restrict__ h1, int N) {
    __shared__ float ws[20 * 32];
    __shared__ float bs[32];
    for (int t = threadIdx.x; t < 640; t += blockDim.x) ws[t] = w[t];
    if (threadIdx.x < 32) bs[threadIdx.x] = b[threadIdx.x];
    __syncthreads();
    int i = blockIdx.x * blockDim.x + threadIdx.x;
    if (i >= N) return;
    float xi[20];
#pragma unroll
    for (int k = 0; k < 20; k++) xi[k] = x[i * 20 + k];
    float acc[32];
#pragma unroll
    for (int j = 0; j < 32; j++) acc[j] = bs[j];
#pragma unroll
    for (int k = 0; k < 20; k++) {
        float a = xi[k];
#pragma unroll
        for (int j = 0; j < 32; j++) acc[j] += a * ws[k * 32 + j];
    }
#pragma unroll
    for (int j = 0; j < 32; j++) {
        float v = acc[j];
        h1[(long)i * 32 + j] = v > 0.f ? v : v * NEG_SLOPE;
    }
}

// ---- gather-propagate + cw accumulation ---------------------------------
// p1[i] = sum_{e in CSR row i} nm * h1[col],  nm = -dinv[i]*attr*dinv[col]
// part==0 lane also does cw[col] += nm (for the pooled layer-3 path).
// 8 threads per node, each owning a float4 slice of the 32 features.
__global__ void gather_kernel(const int* __restrict__ rowptr, const int2* __restrict__ sorted,
                              const float* __restrict__ dinv, const float* __restrict__ h1,
                              float* __restrict__ p1, float* __restrict__ cw, int N) {
    long idx = (long)blockIdx.x * blockDim.x + threadIdx.x;
    int node = (int)(idx >> 3);
    int part = (int)(idx & 7);
    if (node >= N) return;
    int s0 = rowptr[node], s1 = rowptr[node + 1];
    float dr = -dinv[node];
    const float4* h1v = (const float4*)h1;
    float4 acc = make_float4(0.f, 0.f, 0.f, 0.f);
    for (int e = s0; e < s1; e++) {
        int2 pr = sorted[e];
        int c = pr.x;
        float nm = dr * __int_as_float(pr.y) * dinv[c];
        if (part == 0) atomAddF(&cw[c], nm);
        float4 v = h1v[(long)c * 8 + part];
        acc.x += nm * v.x; acc.y += nm * v.y; acc.z += nm * v.z; acc.w += nm * v.w;
    }
    ((float4*)p1)[(long)node * 8 + part] = acc;
}

// ---- h2 = leaky_relu(h1 @ w2_0 + p1 @ w2_1 + b2), 32 -> 64 --------------
__global__ void __launch_bounds__(256, 1)
h2_kernel(const float* __restrict__ h1, const float* __restrict__ p1,
          const float* __restrict__ w0, const float* __restrict__ w1,
          const float* __restrict__ b, float* __restrict__ h2, int N) {
    __shared__ float w0s[32 * 64];
    __shared__ float w1s[32 * 64];
    __shared__ float bs[64];
    for (int t = threadIdx.x; t < 2048; t += blockDim.x) { w0s[t] = w0[t]; w1s[t] = w1[t]; }
    if (threadIdx.x < 64) bs[threadIdx.x] = b[threadIdx.x];
    __syncthreads();
    int i = blockIdx.x * blockDim.x + threadIdx.x;
    if (i >= N) return;
    float acc[64];
#pragma unroll
    for (int j = 0; j < 64; j++) acc[j] = bs[j];
    const float4* h1v = (const float4*)(h1 + (long)i * 32);
    const float4* p1v = (const float4*)(p1 + (long)i * 32);
#pragma unroll
    for (int k4 = 0; k4 < 8; k4++) {
        float4 a = h1v[k4];
        float4 p = p1v[k4];
        float av[4] = {a.x, a.y, a.z, a.w};
        float pv[4] = {p.x, p.y, p.z, p.w};
#pragma unroll
        for (int s = 0; s < 4; s++) {
            int k = k4 * 4 + s;
#pragma unroll
            for (int j = 0; j < 64; j++)
                acc[j] += av[s] * w0s[k * 64 + j] + pv[s] * w1s[k * 64 + j];
        }
    }
#pragma unroll
    for (int j = 0; j < 64; j++) {
        float v = acc[j];
        acc[j] = v > 0.f ? v : v * NEG_SLOPE;
    }
    float4* out = (float4*)(h2 + (long)i * 64);
#pragma unroll
    for (int j = 0; j < 16; j++)
        out[j] = make_float4(acc[4 * j], acc[4 * j + 1], acc[4 * j + 2], acc[4 * j + 3]);
}

// ---- fused pooled sums over h2 ------------------------------------------
// sbuf[j]    += sum_i h2[i][j]           (plain mean path, w3_0)
// sbuf[64+j] += sum_i cw[i] * h2[i][j]   (propagated mean path, w3_1)
__global__ void sum2_kernel(const float* __restrict__ h2, const float* __restrict__ cw,
                            float* __restrict__ sbuf, long total) {
    long tid = (long)blockIdx.x * blockDim.x + threadIdx.x;
    long stride = (long)gridDim.x * blockDim.x;   // multiple of 64
    float a1 = 0.f, a2 = 0.f;
    for (long idx = tid; idx < total; idx += stride) {
        float v = h2[idx];
        a1 += v;
        a2 += cw[idx >> 6] * v;
    }
    __shared__ float red1[256];
    __shared__ float red2[256];
    red1[threadIdx.x] = a1;
    red2[threadIdx.x] = a2;
    __syncthreads();
    if (threadIdx.x < 64) {
        float s1 = red1[threadIdx.x] + red1[threadIdx.x + 64] + red1[threadIdx.x + 128] + red1[threadIdx.x + 192];
        float s2 = red2[threadIdx.x] + red2[threadIdx.x + 64] + red2[threadIdx.x + 128] + red2[threadIdx.x + 192];
        atomAddF(&sbuf[threadIdx.x], s1);
        atomAddF(&sbuf[64 + threadIdx.x], s2);
    }
}

// ---- pooled = (s1/N)@w30 + (s2/N)@w31 + b3; out = log_softmax -----------
__global__ void final_kernel(const float* __restrict__ sbuf,
                             const float* __restrict__ w30, const float* __restrict__ w31,
                             const float* __restrict__ b3, float* __restrict__ out, float invN) {
    if (threadIdx.x != 0 || blockIdx.x != 0) return;
    const float* s1 = sbuf;
    const float* s2 = sbuf + 64;
    float p[2];
    for (int c = 0; c < 2; c++) {
        float a = 0.f;
        for (int k = 0; k < 64; k++) a += s1[k] * w30[k * 2 + c] + s2[k] * w31[k * 2 + c];
        p[c] = a * invN + b3[c];
    }
    float m = fmaxf(p[0], p[1]);
    float lse = m + logf(expf(p[0] - m) + expf(p[1] - m));
    out[0] = p[0] - lse;
    out[1] = p[1] - lse;
}

extern "C" void kernel_launch(void* const* d_in, const int* in_sizes, int n_in,
                              void* d_out, int out_size, void* d_ws, size_t ws_size,
                              hipStream_t stream) {
    const float* x    = (const float*)d_in[0];
    const int*   ei   = (const int*)d_in[1];
    const float* attr = (const float*)d_in[2];
    const float* w1_0 = (const float*)d_in[3];
    const float* b1   = (const float*)d_in[4];
    const float* w2_0 = (const float*)d_in[5];
    const float* w2_1 = (const float*)d_in[6];
    const float* b2   = (const float*)d_in[7];
    const float* w3_0 = (const float*)d_in[8];
    const float* w3_1 = (const float*)d_in[9];
    const float* b3   = (const float*)d_in[10];

    const int N = in_sizes[0] / 20;   // 100000
    const int E = in_sizes[2];        // 3200000
    const int* row = ei;
    const int* col = ei + E;
    const int NB = (N + 255) >> 8;    // 391 buckets (<= 512)

    // workspace layout (words)
    long big = (long)(2L * E > 64L * N ? 2L * E : 64L * N);
    float* ws = (float*)d_ws;
    float* dinv   = ws;                         // N
    float* cw     = ws + N;                     // N
    int*   rowptr = (int*)(ws + 2L * N);        // N+1 (alloc N+4)
    int*   bhist  = (int*)(ws + 3L * N + 4);    // 512
    int*   bbase  = (int*)(ws + 3L * N + 516);  // 512 (+1 slot inside)
    int*   bcursor= (int*)(ws + 3L * N + 1028); // 512
    float* sbuf   = ws + 3L * N + 1540;         // 128
    float* regA   = ws + 3L * N + 1668;         // big: staging, then h1+p1
    float* regB   = regA + big;                 // big: sorted, then h2

    int2*  staging = (int2*)regA;               // dead after finalize
    float* h1      = regA;                      // overlays staging
    float* p1      = regA + 32L * N;
    int2*  sorted  = (int2*)regB;               // dead after gather
    float* h2      = regB;                      // overlays sorted

    // zero accumulated regions (ws is poisoned before every launch)
    hipMemsetAsync(bhist, 0, 512 * 4, stream);
    hipMemsetAsync(cw, 0, (size_t)N * 4, stream);
    hipMemsetAsync(sbuf, 0, 128 * 4, stream);

    const int B = 256;
    bucket_hist_kernel<<<(E + B - 1) / B, B, 0, stream>>>(row, bhist, E, NB);
    bucket_scan_kernel<<<1, 512, 0, stream>>>(bhist, bbase, bcursor, rowptr, NB, N, E);
    bucket_scatter_kernel<<<(E + B - 1) / B, B, 0, stream>>>(row, col, attr, bcursor, staging, E);
    bucket_finalize_kernel<<<NB, 256, 0, stream>>>(bbase, staging, sorted, rowptr, dinv, N);
    h1_kernel<<<(N + B - 1) / B, B, 0, stream>>>(x, w1_0, b1, h1, N);
    {
        long t = (long)N * 8;
        gather_kernel<<<(int)((t + B - 1) / B), B, 0, stream>>>(rowptr, sorted, dinv, h1, p1, cw, N);
    }
    h2_kernel<<<(N + B - 1) / B, B, 0, stream>>>(h1, p1, w2_0, w2_1, b2, h2, N);
    sum2_kernel<<<256, B, 0, stream>>>(h2, cw, sbuf, (long)N * 64);
    final_kernel<<<1, 64, 0, stream>>>(sbuf, w3_0, w3_1, b3, (float*)d_out, 1.0f / (float)N);
}

// Round 5
// 545.888 us; speedup vs baseline: 3.4502x; 3.4502x over previous
//
#include <hip/hip_runtime.h>
#include <hip/hip_bf16.h>

#define NEG_SLOPE 0.01f
#define CH 4096            // edges per block in hist/scatter (LDS-aggregated)
#define PAD 16             // 64B stride for contended global counters
// bucket sort: rows per bucket = 256 (bucket id = row >> 8)
// Packing assumes col < 2^24 and rows-per-bucket = 256 (rowlow in top 8 bits).

__device__ __forceinline__ void atomAddF(float* p, float v) {
    unsafeAtomicAdd(p, v);   // HW global_atomic_add_f32 (avoids CAS fallback)
}

// ---- phase 1: bucket histogram, block-aggregated, padded flush ----------
__global__ void bucket_hist_kernel(const int* __restrict__ row, int* __restrict__ bhist_p,
                                   int E, int NB) {
    __shared__ int lh[512];
    for (int t = threadIdx.x; t < 512; t += 256) lh[t] = 0;
    __syncthreads();
    int base = blockIdx.x * CH;
    int end = min(base + CH, E);
    for (int e = base + threadIdx.x; e < end; e += 256)
        atomicAdd(&lh[row[e] >> 8], 1);
    __syncthreads();
    for (int t = threadIdx.x; t < NB; t += 256)
        if (lh[t]) atomicAdd(&bhist_p[t * PAD], lh[t]);
}

// ---- phase 2: exclusive scan of bucket counts (NB <= 512), init cursors -
__global__ void bucket_scan_kernel(const int* __restrict__ bhist_p, int* __restrict__ bbase,
                                   int* __restrict__ bcursor_p, int* __restrict__ rowptr,
                                   int NB, int N, int E) {
    __shared__ int s[512];
    int t = threadIdx.x;
    int v = (t < NB) ? bhist_p[t * PAD] : 0;
    s[t] = v;
    __syncthreads();
    for (int off = 1; off < 512; off <<= 1) {
        int x = (t >= off) ? s[t - off] : 0;
        __syncthreads();
        s[t] += x;
        __syncthreads();
    }
    if (t < NB) { bbase[t] = s[t] - v; bcursor_p[t * PAD] = s[t] - v; }
    if (t == 0) { bbase[NB] = E; rowptr[N] = E; }
}

// ---- phase 3: block-aggregated scatter into bucket-contiguous staging ---
// One global atomic per (block, non-empty bucket); per-edge position via LDS.
// staging word0 = col | (row&255)<<24 ; word1 = attr bits
__global__ void bucket_scatter_kernel(const int* __restrict__ row, const int* __restrict__ col,
                                      const float* __restrict__ attr, int* __restrict__ bcursor_p,
                                      int2* __restrict__ staging, int E, int NB) {
    __shared__ int lh[512];
    __shared__ int lbase[512];
    __shared__ int lcur[512];
    for (int t = threadIdx.x; t < 512; t += 256) { lh[t] = 0; lcur[t] = 0; }
    __syncthreads();
    int base = blockIdx.x * CH;
    int end = min(base + CH, E);
    for (int e = base + threadIdx.x; e < end; e += 256)
        atomicAdd(&lh[row[e] >> 8], 1);
    __syncthreads();
    for (int t = threadIdx.x; t < NB; t += 256)
        if (lh[t]) lbase[t] = atomicAdd(&bcursor_p[t * PAD], lh[t]);
    __syncthreads();
    for (int e = base + threadIdx.x; e < end; e += 256) {
        int r = row[e], c = col[e];
        int bk = r >> 8;
        int pos = lbase[bk] + atomicAdd(&lcur[bk], 1);
        staging[pos] = make_int2(c | ((r & 255) << 24), __float_as_int(attr[e]));
    }
}

// ---- phase 4: per-bucket finalize: rowptr, dinv, sorted CSR -------------
// One block per bucket. Block owns its 256 rows exclusively -> no global atomics.
__global__ void bucket_finalize_kernel(const int* __restrict__ bbase,
                                       const int2* __restrict__ staging,
                                       int2* __restrict__ sorted, int* __restrict__ rowptr,
                                       float* __restrict__ dinv, int N) {
    __shared__ int lcount[256];
    __shared__ int lscan[256];
    __shared__ float ldeg[256];
    int t = threadIdx.x;
    int b = blockIdx.x;
    int base = bbase[b], end = bbase[b + 1];
    lcount[t] = 0;
    ldeg[t] = 0.f;
    __syncthreads();
    for (int e = base + t; e < end; e += 256) {
        int2 w = staging[e];
        int rl = (w.x >> 24) & 255;
        atomicAdd(&lcount[rl], 1);
        atomicAdd(&ldeg[rl], __int_as_float(w.y));
    }
    __syncthreads();
    lscan[t] = lcount[t];
    __syncthreads();
    for (int off = 1; off < 256; off <<= 1) {
        int x = (t >= off) ? lscan[t - off] : 0;
        __syncthreads();
        lscan[t] += x;
        __syncthreads();
    }
    int excl = lscan[t] - lcount[t];
    int grow = (b << 8) + t;
    if (grow < N) {
        rowptr[grow] = base + excl;
        float d = ldeg[t];
        dinv[grow] = d > 0.f ? rsqrtf(d) : 0.f;
    }
    __syncthreads();
    lcount[t] = excl;           // reuse as local cursor
    __syncthreads();
    for (int e = base + t; e < end; e += 256) {
        int2 w = staging[e];
        int rl = (w.x >> 24) & 255;
        int pos = base + atomicAdd(&lcount[rl], 1);
        sorted[pos] = make_int2(w.x & 0xFFFFFF, w.y);   // {col, attr}
    }
}

// ---- h1 = leaky_relu(x @ w1 + b1), x:(N,20) w:(20,32) -------------------
__global__ void h1_kernel(const float* __restrict__ x, const float* __restrict__ w,
                          const float* __restrict__ b, float* __restrict__ h1, int N) {
    __shared__ float ws[20 * 32];
    __shared__ float bs[32];
    for (int t = threadIdx.x; t < 640; t += blockDim.x) ws[t] = w[t];
    if (threadIdx.x < 32) bs[threadIdx.x] = b[threadIdx.x];
    __syncthreads();
    int i = blockIdx.x * blockDim.x + threadIdx.x;
    if (i >= N) return;
    float xi[20];
#pragma unroll
    for (int k = 0; k < 20; k++) xi[k] = x[i * 20 + k];
    float acc[32];
#pragma unroll
    for (int j = 0; j < 32; j++) acc[j] = bs[j];
#pragma unroll
    for (int k = 0; k < 20; k++) {
        float a = xi[k];
#pragma unroll
        for (int j = 0; j < 32; j++) acc[j] += a * ws[k * 32 + j];
    }
#pragma unroll
    for (int j = 0; j < 32; j++) {
        float v = acc[j];
        h1[(long)i * 32 + j] = v > 0.f ? v : v * NEG_SLOPE;
    }
}

// ---- gather-propagate + cw accumulation ---------------------------------
// p1[i] = sum_{e in CSR row i} nm * h1[col],  nm = -dinv[i]*attr*dinv[col]
// part==0 lane also does cw[col] += nm (for the pooled layer-3 path).
// 8 threads per node, each owning a float4 slice of the 32 features.
__global__ void gather_kernel(const int* __restrict__ rowptr, const int2* __restrict__ sorted,
                              const float* __restrict__ dinv, const float* __restrict__ h1,
                              float* __restrict__ p1, float* __restrict__ cw, int N) {
    long idx = (long)blockIdx.x * blockDim.x + threadIdx.x;
    int node = (int)(idx >> 3);
    int part = (int)(idx & 7);
    if (node >= N) return;
    int s0 = rowptr[node], s1 = rowptr[node + 1];
    float dr = -dinv[node];
    const float4* h1v = (const float4*)h1;
    float4 acc = make_float4(0.f, 0.f, 0.f, 0.f);
    for (int e = s0; e < s1; e++) {
        int2 pr = sorted[e];
        int c = pr.x;
        float nm = dr * __int_as_float(pr.y) * dinv[c];
        if (part == 0) atomAddF(&cw[c], nm);
        float4 v = h1v[(long)c * 8 + part];
        acc.x += nm * v.x; acc.y += nm * v.y; acc.z += nm * v.z; acc.w += nm * v.w;
    }
    ((float4*)p1)[(long)node * 8 + part] = acc;
}

// ---- h2 = leaky_relu(h1 @ w2_0 + p1 @ w2_1 + b2), 32 -> 64 --------------
__global__ void __launch_bounds__(256, 1)
h2_kernel(const float* __restrict__ h1, const float* __restrict__ p1,
          const float* __restrict__ w0, const float* __restrict__ w1,
          const float* __restrict__ b, float* __restrict__ h2, int N) {
    __shared__ float w0s[32 * 64];
    __shared__ float w1s[32 * 64];
    __shared__ float bs[64];
    for (int t = threadIdx.x; t < 2048; t += blockDim.x) { w0s[t] = w0[t]; w1s[t] = w1[t]; }
    if (threadIdx.x < 64) bs[threadIdx.x] = b[threadIdx.x];
    __syncthreads();
    int i = blockIdx.x * blockDim.x + threadIdx.x;
    if (i >= N) return;
    float acc[64];
#pragma unroll
    for (int j = 0; j < 64; j++) acc[j] = bs[j];
    const float4* h1v = (const float4*)(h1 + (long)i * 32);
    const float4* p1v = (const float4*)(p1 + (long)i * 32);
#pragma unroll
    for (int k4 = 0; k4 < 8; k4++) {
        float4 a = h1v[k4];
        float4 p = p1v[k4];
        float av[4] = {a.x, a.y, a.z, a.w};
        float pv[4] = {p.x, p.y, p.z, p.w};
#pragma unroll
        for (int s = 0; s < 4; s++) {
            int k = k4 * 4 + s;
#pragma unroll
            for (int j = 0; j < 64; j++)
                acc[j] += av[s] * w0s[k * 64 + j] + pv[s] * w1s[k * 64 + j];
        }
    }
#pragma unroll
    for (int j = 0; j < 64; j++) {
        float v = acc[j];
        acc[j] = v > 0.f ? v : v * NEG_SLOPE;
    }
    float4* out = (float4*)(h2 + (long)i * 64);
#pragma unroll
    for (int j = 0; j < 16; j++)
        out[j] = make_float4(acc[4 * j], acc[4 * j + 1], acc[4 * j + 2], acc[4 * j + 3]);
}

// ---- fused pooled sums over h2 ------------------------------------------
// sbuf[j]    += sum_i h2[i][j]           (plain mean path, w3_0)
// sbuf[64+j] += sum_i cw[i] * h2[i][j]   (propagated mean path, w3_1)
__global__ void sum2_kernel(const float* __restrict__ h2, const float* __restrict__ cw,
                            float* __restrict__ sbuf, long total) {
    long tid = (long)blockIdx.x * blockDim.x + threadIdx.x;
    long stride = (long)gridDim.x * blockDim.x;   // multiple of 64
    float a1 = 0.f, a2 = 0.f;
    for (long idx = tid; idx < total; idx += stride) {
        float v = h2[idx];
        a1 += v;
        a2 += cw[idx >> 6] * v;
    }
    __shared__ float red1[256];
    __shared__ float red2[256];
    red1[threadIdx.x] = a1;
    red2[threadIdx.x] = a2;
    __syncthreads();
    if (threadIdx.x < 64) {
        float s1 = red1[threadIdx.x] + red1[threadIdx.x + 64] + red1[threadIdx.x + 128] + red1[threadIdx.x + 192];
        float s2 = red2[threadIdx.x] + red2[threadIdx.x + 64] + red2[threadIdx.x + 128] + red2[threadIdx.x + 192];
        atomAddF(&sbuf[threadIdx.x], s1);
        atomAddF(&sbuf[64 + threadIdx.x], s2);
    }
}

// ---- pooled = (s1/N)@w30 + (s2/N)@w31 + b3; out = log_softmax -----------
__global__ void final_kernel(const float* __restrict__ sbuf,
                             const float* __restrict__ w30, const float* __restrict__ w31,
                             const float* __restrict__ b3, float* __restrict__ out, float invN) {
    if (threadIdx.x != 0 || blockIdx.x != 0) return;
    const float* s1 = sbuf;
    const float* s2 = sbuf + 64;
    float p[2];
    for (int c = 0; c < 2; c++) {
        float a = 0.f;
        for (int k = 0; k < 64; k++) a += s1[k] * w30[k * 2 + c] + s2[k] * w31[k * 2 + c];
        p[c] = a * invN + b3[c];
    }
    float m = fmaxf(p[0], p[1]);
    float lse = m + logf(expf(p[0] - m) + expf(p[1] - m));
    out[0] = p[0] - lse;
    out[1] = p[1] - lse;
}

extern "C" void kernel_launch(void* const* d_in, const int* in_sizes, int n_in,
                              void* d_out, int out_size, void* d_ws, size_t ws_size,
                              hipStream_t stream) {
    const float* x    = (const float*)d_in[0];
    const int*   ei   = (const int*)d_in[1];
    const float* attr = (const float*)d_in[2];
    const float* w1_0 = (const float*)d_in[3];
    const float* b1   = (const float*)d_in[4];
    const float* w2_0 = (const float*)d_in[5];
    const float* w2_1 = (const float*)d_in[6];
    const float* b2   = (const float*)d_in[7];
    const float* w3_0 = (const float*)d_in[8];
    const float* w3_1 = (const float*)d_in[9];
    const float* b3   = (const float*)d_in[10];

    const int N = in_sizes[0] / 20;   // 100000
    const int E = in_sizes[2];        // 3200000
    const int* row = ei;
    const int* col = ei + E;
    const int NB = (N + 255) >> 8;    // 391 buckets (<= 512)

    // workspace layout (words)
    long big = (long)(2L * E > 64L * N ? 2L * E : 64L * N);
    float* ws = (float*)d_ws;
    float* dinv     = ws;                          // N
    float* cw       = ws + N;                      // N
    int*   rowptr   = (int*)(ws + 2L * N);         // N+1 (alloc N+4)
    int*   bhist_p  = (int*)(ws + 3L * N + 4);     // 512*PAD
    int*   bbase    = (int*)(ws + 3L * N + 4 + 512L * PAD);          // 513 (alloc 516)
    int*   bcursor_p= (int*)(ws + 3L * N + 520 + 512L * PAD);        // 512*PAD
    float* sbuf     = ws + 3L * N + 520 + 1024L * PAD;               // 128
    float* regA     = ws + 3L * N + 648 + 1024L * PAD;  // big: staging, then h1+p1
    float* regB     = regA + big;                       // big: sorted, then h2

    int2*  staging = (int2*)regA;               // dead after finalize
    float* h1      = regA;                      // overlays staging
    float* p1      = regA + 32L * N;
    int2*  sorted  = (int2*)regB;               // dead after gather
    float* h2      = regB;                      // overlays sorted

    // zero accumulated regions (ws is poisoned before every launch)
    hipMemsetAsync(bhist_p, 0, 512 * PAD * 4, stream);
    hipMemsetAsync(cw, 0, (size_t)N * 4, stream);
    hipMemsetAsync(sbuf, 0, 128 * 4, stream);

    const int B = 256;
    const int NCH = (E + CH - 1) / CH;   // chunk-blocks for hist/scatter
    bucket_hist_kernel<<<NCH, B, 0, stream>>>(row, bhist_p, E, NB);
    bucket_scan_kernel<<<1, 512, 0, stream>>>(bhist_p, bbase, bcursor_p, rowptr, NB, N, E);
    bucket_scatter_kernel<<<NCH, B, 0, stream>>>(row, col, attr, bcursor_p, staging, E, NB);
    bucket_finalize_kernel<<<NB, 256, 0, stream>>>(bbase, staging, sorted, rowptr, dinv, N);
    h1_kernel<<<(N + B - 1) / B, B, 0, stream>>>(x, w1_0, b1, h1, N);
    {
        long t = (long)N * 8;
        gather_kernel<<<(int)((t + B - 1) / B), B, 0, stream>>>(rowptr, sorted, dinv, h1, p1, cw, N);
    }
    h2_kernel<<<(N + B - 1) / B, B, 0, stream>>>(h1, p1, w2_0, w2_1, b2, h2, N);
    sum2_kernel<<<256, B, 0, stream>>>(h2, cw, sbuf, (long)N * 64);
    final_kernel<<<1, 64, 0, stream>>>(sbuf, w3_0, w3_1, b3, (float*)d_out, 1.0f / (float)N);
}

// Round 6
// 532.672 us; speedup vs baseline: 3.5358x; 1.0248x over previous
//
#include <hip/hip_runtime.h>
#include <hip/hip_bf16.h>

#define NEG_SLOPE 0.01f
#define CH 4096            // edges per block in hist/scatter (LDS-aggregated)
#define PAD 16             // 64B stride for contended global counters
// bucket sort: rows per bucket = 256 (bucket id = row >> 8)
// Packing assumes col < 2^24 and rows-per-bucket = 256 (rowlow in top 8 bits).

__device__ __forceinline__ void atomAddF(float* p, float v) {
    unsafeAtomicAdd(p, v);   // HW global_atomic_add_f32 (avoids CAS fallback)
}

// ---- phase 1: bucket histogram, block-aggregated, padded flush ----------
__global__ void bucket_hist_kernel(const int* __restrict__ row, int* __restrict__ bhist_p,
                                   int E, int NB) {
    __shared__ int lh[512];
    for (int t = threadIdx.x; t < 512; t += 256) lh[t] = 0;
    __syncthreads();
    int base = blockIdx.x * CH;
    int end = min(base + CH, E);
    for (int e = base + threadIdx.x; e < end; e += 256)
        atomicAdd(&lh[row[e] >> 8], 1);
    __syncthreads();
    for (int t = threadIdx.x; t < NB; t += 256)
        if (lh[t]) atomicAdd(&bhist_p[t * PAD], lh[t]);
}

// ---- phase 2: exclusive scan of bucket counts (NB <= 512), init cursors -
__global__ void bucket_scan_kernel(const int* __restrict__ bhist_p, int* __restrict__ bbase,
                                   int* __restrict__ bcursor_p, int* __restrict__ rowptr,
                                   int NB, int N, int E) {
    __shared__ int s[512];
    int t = threadIdx.x;
    int v = (t < NB) ? bhist_p[t * PAD] : 0;
    s[t] = v;
    __syncthreads();
    for (int off = 1; off < 512; off <<= 1) {
        int x = (t >= off) ? s[t - off] : 0;
        __syncthreads();
        s[t] += x;
        __syncthreads();
    }
    if (t < NB) { bbase[t] = s[t] - v; bcursor_p[t * PAD] = s[t] - v; }
    if (t == 0) { bbase[NB] = E; rowptr[N] = E; }
}

// ---- phase 3: block-aggregated scatter into bucket-contiguous staging ---
// One global atomic per (block, non-empty bucket); per-edge position via LDS.
// staging word0 = col | (row&255)<<24 ; word1 = attr bits
__global__ void bucket_scatter_kernel(const int* __restrict__ row, const int* __restrict__ col,
                                      const float* __restrict__ attr, int* __restrict__ bcursor_p,
                                      int2* __restrict__ staging, int E, int NB) {
    __shared__ int lh[512];
    __shared__ int lbase[512];
    __shared__ int lcur[512];
    for (int t = threadIdx.x; t < 512; t += 256) { lh[t] = 0; lcur[t] = 0; }
    __syncthreads();
    int base = blockIdx.x * CH;
    int end = min(base + CH, E);
    for (int e = base + threadIdx.x; e < end; e += 256)
        atomicAdd(&lh[row[e] >> 8], 1);
    __syncthreads();
    for (int t = threadIdx.x; t < NB; t += 256)
        if (lh[t]) lbase[t] = atomicAdd(&bcursor_p[t * PAD], lh[t]);
    __syncthreads();
    for (int e = base + threadIdx.x; e < end; e += 256) {
        int r = row[e], c = col[e];
        int bk = r >> 8;
        int pos = lbase[bk] + atomicAdd(&lcur[bk], 1);
        staging[pos] = make_int2(c | ((r & 255) << 24), __float_as_int(attr[e]));
    }
}

// ---- phase 4: per-bucket finalize: rowptr, dinv, sorted CSR -------------
// One block per bucket; block owns its 256 rows exclusively -> no global atomics.
// sorted.y is pre-scaled: pre = -dinv[row] * attr  (gather multiplies by dinv[col])
__global__ void bucket_finalize_kernel(const int* __restrict__ bbase,
                                       const int2* __restrict__ staging,
                                       int2* __restrict__ sorted, int* __restrict__ rowptr,
                                       float* __restrict__ dinv, int N) {
    __shared__ int lcount[256];
    __shared__ int lscan[256];
    __shared__ float ldeg[256];
    __shared__ float sdinv[256];
    int t = threadIdx.x;
    int b = blockIdx.x;
    int base = bbase[b], end = bbase[b + 1];
    lcount[t] = 0;
    ldeg[t] = 0.f;
    __syncthreads();
    for (int e = base + t; e < end; e += 256) {
        int2 w = staging[e];
        int rl = (w.x >> 24) & 255;
        atomicAdd(&lcount[rl], 1);
        atomicAdd(&ldeg[rl], __int_as_float(w.y));
    }
    __syncthreads();
    lscan[t] = lcount[t];
    __syncthreads();
    for (int off = 1; off < 256; off <<= 1) {
        int x = (t >= off) ? lscan[t - off] : 0;
        __syncthreads();
        lscan[t] += x;
        __syncthreads();
    }
    int excl = lscan[t] - lcount[t];
    int grow = (b << 8) + t;
    float d = ldeg[t];
    float di = d > 0.f ? rsqrtf(d) : 0.f;
    sdinv[t] = di;
    if (grow < N) {
        rowptr[grow] = base + excl;
        dinv[grow] = di;
    }
    __syncthreads();
    lcount[t] = excl;           // reuse as local cursor
    __syncthreads();
    for (int e = base + t; e < end; e += 256) {
        int2 w = staging[e];
        int rl = (w.x >> 24) & 255;
        int pos = base + atomicAdd(&lcount[rl], 1);
        float pre = -sdinv[rl] * __int_as_float(w.y);
        sorted[pos] = make_int2(w.x & 0xFFFFFF, __float_as_int(pre));   // {col, pre}
    }
}

// ---- h1 = leaky_relu(x @ w1 + b1), x:(N,20) w:(20,32) -------------------
__global__ void h1_kernel(const float* __restrict__ x, const float* __restrict__ w,
                          const float* __restrict__ b, float* __restrict__ h1, int N) {
    __shared__ float ws[20 * 32];
    __shared__ float bs[32];
    for (int t = threadIdx.x; t < 640; t += blockDim.x) ws[t] = w[t];
    if (threadIdx.x < 32) bs[threadIdx.x] = b[threadIdx.x];
    __syncthreads();
    int i = blockIdx.x * blockDim.x + threadIdx.x;
    if (i >= N) return;
    float xi[20];
#pragma unroll
    for (int k = 0; k < 20; k++) xi[k] = x[i * 20 + k];
    float acc[32];
#pragma unroll
    for (int j = 0; j < 32; j++) acc[j] = bs[j];
#pragma unroll
    for (int k = 0; k < 20; k++) {
        float a = xi[k];
#pragma unroll
        for (int j = 0; j < 32; j++) acc[j] += a * ws[k * 32 + j];
    }
#pragma unroll
    for (int j = 0; j < 32; j++) {
        float v = acc[j];
        h1[(long)i * 32 + j] = v > 0.f ? v : v * NEG_SLOPE;
    }
}

// ---- gather-propagate + cw accumulation (4x unrolled for MLP) -----------
// p1[i] = sum_{e in CSR row i} (pre * dinv[col]) * h1[col]
// part==0 lane also does cw[col] += nm (for the pooled layer-3 path).
// 8 threads per node, each owning a float4 slice of the 32 features.
__global__ void gather_kernel(const int* __restrict__ rowptr, const int2* __restrict__ sorted,
                              const float* __restrict__ dinv, const float* __restrict__ h1,
                              float* __restrict__ p1g, float* __restrict__ cw, int N) {
    long idx = (long)blockIdx.x * blockDim.x + threadIdx.x;
    int node = (int)(idx >> 3);
    int part = (int)(idx & 7);
    if (node >= N) return;
    int s0 = rowptr[node], s1 = rowptr[node + 1];
    const float4* h1v = (const float4*)h1;
    float4 acc = make_float4(0.f, 0.f, 0.f, 0.f);
    int e = s0;
    for (; e + 4 <= s1; e += 4) {
        int2 q0 = sorted[e], q1 = sorted[e + 1], q2 = sorted[e + 2], q3 = sorted[e + 3];
        int c0 = q0.x, c1 = q1.x, c2 = q2.x, c3 = q3.x;
        float d0 = dinv[c0], d1 = dinv[c1], d2 = dinv[c2], d3 = dinv[c3];
        float4 v0 = h1v[(long)c0 * 8 + part];
        float4 v1 = h1v[(long)c1 * 8 + part];
        float4 v2 = h1v[(long)c2 * 8 + part];
        float4 v3 = h1v[(long)c3 * 8 + part];
        float n0 = __int_as_float(q0.y) * d0;
        float n1 = __int_as_float(q1.y) * d1;
        float n2 = __int_as_float(q2.y) * d2;
        float n3 = __int_as_float(q3.y) * d3;
        if (part == 0) {
            atomAddF(&cw[c0], n0); atomAddF(&cw[c1], n1);
            atomAddF(&cw[c2], n2); atomAddF(&cw[c3], n3);
        }
        acc.x += n0 * v0.x + n1 * v1.x + n2 * v2.x + n3 * v3.x;
        acc.y += n0 * v0.y + n1 * v1.y + n2 * v2.y + n3 * v3.y;
        acc.z += n0 * v0.z + n1 * v1.z + n2 * v2.z + n3 * v3.z;
        acc.w += n0 * v0.w + n1 * v1.w + n2 * v2.w + n3 * v3.w;
    }
    for (; e < s1; e++) {
        int2 q = sorted[e];
        int c = q.x;
        float nm = __int_as_float(q.y) * dinv[c];
        if (part == 0) atomAddF(&cw[c], nm);
        float4 v = h1v[(long)c * 8 + part];
        acc.x += nm * v.x; acc.y += nm * v.y; acc.z += nm * v.z; acc.w += nm * v.w;
    }
    ((float4*)p1g)[(long)node * 8 + part] = acc;
}

// ---- h2 = leaky_relu(h1 @ w2_0 + p1 @ w2_1 + b2), 32 -> 64 --------------
__global__ void __launch_bounds__(256, 1)
h2_kernel(const float* __restrict__ h1, const float* __restrict__ p1,
          const float* __restrict__ w0, const float* __restrict__ w1,
          const float* __restrict__ b, float* __restrict__ h2, int N) {
    __shared__ float w0s[32 * 64];
    __shared__ float w1s[32 * 64];
    __shared__ float bs[64];
    for (int t = threadIdx.x; t < 2048; t += blockDim.x) { w0s[t] = w0[t]; w1s[t] = w1[t]; }
    if (threadIdx.x < 64) bs[threadIdx.x] = b[threadIdx.x];
    __syncthreads();
    int i = blockIdx.x * blockDim.x + threadIdx.x;
    if (i >= N) return;
    const float4* w0v = (const float4*)w0s;   // [k*16 + j4]
    const float4* w1v = (const float4*)w1s;
    const float4* bv  = (const float4*)bs;
    float4 acc[16];
#pragma unroll
    for (int j4 = 0; j4 < 16; j4++) acc[j4] = bv[j4];
    const float4* h1v = (const float4*)(h1 + (long)i * 32);
    const float4* p1v = (const float4*)(p1 + (long)i * 32);
#pragma unroll
    for (int k4 = 0; k4 < 8; k4++) {
        float4 a = h1v[k4];
        float4 p = p1v[k4];
        float av[4] = {a.x, a.y, a.z, a.w};
        float pv[4] = {p.x, p.y, p.z, p.w};
#pragma unroll
        for (int s = 0; s < 4; s++) {
            int k = k4 * 4 + s;
            float aa = av[s], pp = pv[s];
#pragma unroll
            for (int j4 = 0; j4 < 16; j4++) {
                float4 w0r = w0v[k * 16 + j4];
                float4 w1r = w1v[k * 16 + j4];
                acc[j4].x += aa * w0r.x + pp * w1r.x;
                acc[j4].y += aa * w0r.y + pp * w1r.y;
                acc[j4].z += aa * w0r.z + pp * w1r.z;
                acc[j4].w += aa * w0r.w + pp * w1r.w;
            }
        }
    }
    float4* out = (float4*)(h2 + (long)i * 64);
#pragma unroll
    for (int j4 = 0; j4 < 16; j4++) {
        float4 v = acc[j4];
        v.x = v.x > 0.f ? v.x : v.x * NEG_SLOPE;
        v.y = v.y > 0.f ? v.y : v.y * NEG_SLOPE;
        v.z = v.z > 0.f ? v.z : v.z * NEG_SLOPE;
        v.w = v.w > 0.f ? v.w : v.w * NEG_SLOPE;
        out[j4] = v;
    }
}

// ---- fused pooled sums over h2 ------------------------------------------
// sbuf[j]    += sum_i h2[i][j]           (plain mean path, w3_0)
// sbuf[64+j] += sum_i cw[i] * h2[i][j]   (propagated mean path, w3_1)
__global__ void sum2_kernel(const float* __restrict__ h2, const float* __restrict__ cw,
                            float* __restrict__ sbuf, long total) {
    long tid = (long)blockIdx.x * blockDim.x + threadIdx.x;
    long stride = (long)gridDim.x * blockDim.x;   // multiple of 64
    float a1 = 0.f, a2 = 0.f;
    for (long idx = tid; idx < total; idx += stride) {
        float v = h2[idx];
        a1 += v;
        a2 += cw[idx >> 6] * v;
    }
    __shared__ float red1[256];
    __shared__ float red2[256];
    red1[threadIdx.x] = a1;
    red2[threadIdx.x] = a2;
    __syncthreads();
    if (threadIdx.x < 64) {
        float s1 = red1[threadIdx.x] + red1[threadIdx.x + 64] + red1[threadIdx.x + 128] + red1[threadIdx.x + 192];
        float s2 = red2[threadIdx.x] + red2[threadIdx.x + 64] + red2[threadIdx.x + 128] + red2[threadIdx.x + 192];
        atomAddF(&sbuf[threadIdx.x], s1);
        atomAddF(&sbuf[64 + threadIdx.x], s2);
    }
}

// ---- pooled = (s1/N)@w30 + (s2/N)@w31 + b3; out = log_softmax -----------
__global__ void final_kernel(const float* __restrict__ sbuf,
                             const float* __restrict__ w30, const float* __restrict__ w31,
                             const float* __restrict__ b3, float* __restrict__ out, float invN) {
    if (threadIdx.x != 0 || blockIdx.x != 0) return;
    const float* s1 = sbuf;
    const float* s2 = sbuf + 64;
    float p[2];
    for (int c = 0; c < 2; c++) {
        float a = 0.f;
        for (int k = 0; k < 64; k++) a += s1[k] * w30[k * 2 + c] + s2[k] * w31[k * 2 + c];
        p[c] = a * invN + b3[c];
    }
    float m = fmaxf(p[0], p[1]);
    float lse = m + logf(expf(p[0] - m) + expf(p[1] - m));
    out[0] = p[0] - lse;
    out[1] = p[1] - lse;
}

extern "C" void kernel_launch(void* const* d_in, const int* in_sizes, int n_in,
                              void* d_out, int out_size, void* d_ws, size_t ws_size,
                              hipStream_t stream) {
    const float* x    = (const float*)d_in[0];
    const int*   ei   = (const int*)d_in[1];
    const float* attr = (const float*)d_in[2];
    const float* w1_0 = (const float*)d_in[3];
    const float* b1   = (const float*)d_in[4];
    const float* w2_0 = (const float*)d_in[5];
    const float* w2_1 = (const float*)d_in[6];
    const float* b2   = (const float*)d_in[7];
    const float* w3_0 = (const float*)d_in[8];
    const float* w3_1 = (const float*)d_in[9];
    const float* b3   = (const float*)d_in[10];

    const int N = in_sizes[0] / 20;   // 100000
    const int E = in_sizes[2];        // 3200000
    const int* row = ei;
    const int* col = ei + E;
    const int NB = (N + 255) >> 8;    // 391 buckets (<= 512)

    // workspace layout (words)
    long big = (long)(2L * E > 64L * N ? 2L * E : 64L * N);
    float* ws = (float*)d_ws;
    float* dinv     = ws;                          // N
    float* cw       = ws + N;                      // N
    int*   rowptr   = (int*)(ws + 2L * N);         // N+1 (alloc N+4)
    int*   bhist_p  = (int*)(ws + 3L * N + 4);     // 512*PAD
    int*   bbase    = (int*)(ws + 3L * N + 4 + 512L * PAD);          // 513 (alloc 516)
    int*   bcursor_p= (int*)(ws + 3L * N + 520 + 512L * PAD);        // 512*PAD
    float* sbuf     = ws + 3L * N + 520 + 1024L * PAD;               // 128
    float* regA     = ws + 3L * N + 648 + 1024L * PAD;  // big: staging, then h1+p1
    float* regB     = regA + big;                       // big: sorted, then h2

    int2*  staging = (int2*)regA;               // dead after finalize
    float* h1      = regA;                      // overlays staging
    float* p1      = regA + 32L * N;
    int2*  sorted  = (int2*)regB;               // dead after gather
    float* h2      = regB;                      // overlays sorted

    // zero accumulated regions (ws is poisoned before every launch)
    hipMemsetAsync(bhist_p, 0, 512 * PAD * 4, stream);
    hipMemsetAsync(cw, 0, (size_t)N * 4, stream);
    hipMemsetAsync(sbuf, 0, 128 * 4, stream);

    const int B = 256;
    const int NCH = (E + CH - 1) / CH;   // chunk-blocks for hist/scatter
    bucket_hist_kernel<<<NCH, B, 0, stream>>>(row, bhist_p, E, NB);
    bucket_scan_kernel<<<1, 512, 0, stream>>>(bhist_p, bbase, bcursor_p, rowptr, NB, N, E);
    bucket_scatter_kernel<<<NCH, B, 0, stream>>>(row, col, attr, bcursor_p, staging, E, NB);
    bucket_finalize_kernel<<<NB, 256, 0, stream>>>(bbase, staging, sorted, rowptr, dinv, N);
    h1_kernel<<<(N + B - 1) / B, B, 0, stream>>>(x, w1_0, b1, h1, N);
    {
        long t = (long)N * 8;
        gather_kernel<<<(int)((t + B - 1) / B), B, 0, stream>>>(rowptr, sorted, dinv, h1, p1, cw, N);
    }
    h2_kernel<<<(N + B - 1) / B, B, 0, stream>>>(h1, p1, w2_0, w2_1, b2, h2, N);
    sum2_kernel<<<256, B, 0, stream>>>(h2, cw, sbuf, (long)N * 64);
    final_kernel<<<1, 64, 0, stream>>>(sbuf, w3_0, w3_1, b3, (float*)d_out, 1.0f / (float)N);
}